// Round 1
// baseline (53.628 us; speedup 1.0000x reference)
//
#include <hip/hip_runtime.h>

// 9x9 clipped box-SUM on (8,3,1024,1024) f32, fused single pass.
// Wave = 64 lanes: 56 output columns + 4-wide halo each side.
// Vertical: per-lane rolling window sum (register ring buffer, unroll-9).
// Horizontal: 5-shuffle sliding-window sum across lanes.

constexpr int H = 1024, W = 1024;
constexpr int RAD = 4;
constexpr int OUTW = 56;            // 64 - 2*RAD outputs per wave
constexpr int NSTRIP = 19;          // ceil(W / OUTW): 19*56 = 1064
constexpr int CHUNK = 128;
constexpr int NCHUNK = H / CHUNK;   // 8
constexpr int NIMG = 24;            // 8 * 3

__global__ __launch_bounds__(256) void box9_kernel(const float* __restrict__ x,
                                                   float* __restrict__ out) {
    const int lane = threadIdx.x & 63;
    const int wid  = blockIdx.x * 4 + (threadIdx.x >> 6);

    const int chunk = wid & (NCHUNK - 1);   // NCHUNK = 8
    const int t     = wid >> 3;
    const int strip = t % NSTRIP;
    const int img   = t / NSTRIP;

    const int  c   = strip * OUTW - RAD + lane;       // column this lane tracks
    const bool cok = ((unsigned)c < (unsigned)W);
    const float* xp = x + (size_t)img * (H * W) + (cok ? c : 0);
    float*       op = out + (size_t)img * (H * W);

    const int h0 = chunk * CHUNK;
    const int h1 = h0 + CHUNK;

    // Warm-up: ring holds x[h0-4 .. h0+4] for this column; V = their sum.
    float ring[9];
    float V = 0.f;
#pragma unroll
    for (int j = 0; j < 9; ++j) {
        const int row = h0 - RAD + j;
        float v = 0.f;
        if (cok && row >= 0 && row < H) v = xp[(size_t)row * W];
        ring[j] = v;
        V += v;
    }

    const bool wok = (lane >= RAD) && (lane < OUTW + RAD) && ((unsigned)c < (unsigned)W);

    int h = h0;
    while (h < h1) {
        // Prefetch the 9 rows this group consumes (x[h+5 .. h+13]) so the
        // serial V-dependence doesn't expose load latency.
        float nxt[9];
#pragma unroll
        for (int u = 0; u < 9; ++u) {
            const int row = h + RAD + 1 + u;
            nxt[u] = (cok && row < H && (h + u) < h1) ? xp[(size_t)row * W] : 0.f;
        }
#pragma unroll
        for (int u = 0; u < 9; ++u) {
            if (h >= h1) break;
            // Sliding 9-wide sum across lanes: out[l] = sum V[l-4 .. l+4].
            float s2 = V  + __shfl(V,  lane + 1);
            float s4 = s2 + __shfl(s2, lane + 2);
            float s8 = s4 + __shfl(s4, lane + 4);
            float s9 = s8 + __shfl(V,  lane + 8);   // V[l .. l+8]
            float o  = __shfl(s9, lane - 4);        // V[l-4 .. l+4]
            if (wok) op[(size_t)h * W + c] = o;
            // Roll vertical window: add x[h+5], drop x[h-4].
            V += nxt[u] - ring[u];
            ring[u] = nxt[u];
            ++h;
        }
    }
}

extern "C" void kernel_launch(void* const* d_in, const int* in_sizes, int n_in,
                              void* d_out, int out_size, void* d_ws, size_t ws_size,
                              hipStream_t stream) {
    const float* x   = (const float*)d_in[0];
    float*       out = (float*)d_out;
    const int n_waves  = NIMG * NSTRIP * NCHUNK;      // 3648
    const int n_blocks = n_waves / 4;                 // 912 blocks of 4 waves
    box9_kernel<<<dim3(n_blocks), dim3(256), 0, stream>>>(x, out);
}